// Round 8
// baseline (133.688 us; speedup 1.0000x reference)
//
#include <hip/hip_runtime.h>
#include <hip/hip_bf16.h>

typedef __attribute__((ext_vector_type(4))) float f32x4;
typedef __attribute__((ext_vector_type(8))) __bf16 bf16x8;
typedef __attribute__((ext_vector_type(4))) unsigned int uint4v;

constexpr int M = 16384;
constexpr int N = 1024;
constexpr int K = 2048;
constexpr int BM = 256, BN = 256, BK = 64;  // 8-phase template, BK=64
constexpr int NKT = K / BK;                 // 32 K-tiles
constexpr float BN_EPS = 1e-5f;
constexpr int TM2 = M / BM;  // 64 row-tiles (psum partials)

// async 16B global -> LDS (lds dest must be wave-uniform; HW adds lane*16)
#define GLOAD_LDS16(g, l)                                                      \
  __builtin_amdgcn_global_load_lds(                                            \
      (const __attribute__((address_space(1))) void*)(g),                      \
      (__attribute__((address_space(3))) void*)(l), 16, 0, 0)

#define SB0 __builtin_amdgcn_sched_barrier(0)
#define BARRIER __builtin_amdgcn_s_barrier()
#define LGKM0 asm volatile("s_waitcnt lgkmcnt(0)" ::: "memory")
#define VMC(n) asm volatile("s_waitcnt vmcnt(" #n ")" ::: "memory")

__device__ __forceinline__ unsigned sgnbf(float f) {
  return (f >= 0.f) ? 0x3F80u : 0xBF80u;
}
__global__ __launch_bounds__(256) void binw_kernel(
    const float* __restrict__ w, uint4v* __restrict__ wb) {
  size_t i = (size_t)blockIdx.x * 256 + threadIdx.x;
  const f32x4* win = (const f32x4*)w;
  f32x4 v0 = win[i * 2];
  f32x4 v1 = win[i * 2 + 1];
  uint4v o;
  o.x = sgnbf(v0[0]) | (sgnbf(v0[1]) << 16);
  o.y = sgnbf(v0[2]) | (sgnbf(v0[3]) << 16);
  o.z = sgnbf(v1[0]) | (sgnbf(v1[1]) << 16);
  o.w = sgnbf(v1[2]) | (sgnbf(v1[3]) << 16);
  wb[i] = o;
}

// ---- x fp32 -> bf16 pre-cast (one pass; removes reg-staging from GEMM) ----
__global__ __launch_bounds__(256) void castx_kernel(
    const float* __restrict__ x, unsigned short* __restrict__ xb) {
  const size_t i = ((size_t)blockIdx.x * 256 + threadIdx.x) * 8;
  f32x4 a = *(const f32x4*)(x + i);
  f32x4 b = *(const f32x4*)(x + i + 4);
  bf16x8 v;
#pragma unroll
  for (int j = 0; j < 4; ++j) {
    v[j] = (__bf16)a[j];
    v[4 + j] = (__bf16)b[j];
  }
  *(bf16x8*)(xb + i) = v;
}

// ---- PATH A: pure-DMA m201-style GEMM (both operands bf16 gload_lds) ----
// 512 thr = 8 waves (2M x 4N), wave tile 128x64, acc[8][4], 2-slot LDS.
// K-tile = two 32-k planes of 64B rows, chunk XOR (row>>1)&3 involution
// (harness-verified 0-conflict atom, R0/R4/R7). Staging: tile t+1's 16 DMA
// units (A 8 + B 8 per block; 4+4 per wave) issued at ph0/ph1, drained by
// vmcnt(0) only at ph3-end (>=2-phase cover); no VGPR round-trip, no cvt,
// no ds_write -> removes the m151-measured 26% reg-staging penalty that
// pinned R0/R3/R4/R6/R7 at the ~870 TF m97-family wall.
__global__ __launch_bounds__(512, 2) void gemm_dma_kernel(
    const unsigned short* __restrict__ Axb, const unsigned short* __restrict__ B,
    float* __restrict__ Y, float* __restrict__ psum, float* __restrict__ psq) {
  __shared__ unsigned short Asd[2][2][8192];  // [slot][plane][row*32+chunk*8]
  __shared__ unsigned short Bsd[2][2][8192];  // 64 KiB each
  __shared__ float redsum[2][256];            // 2 KiB
  __shared__ float redsq[2][256];             // 2 KiB

  const int tid = threadIdx.x;
  const int wid = tid >> 6;
  const int lane = tid & 63;
  const int wr = wid >> 2, wc = wid & 3;  // 2x4 wave grid, wave owns 128x64

  // T1: XCD swizzle (grid 256, %8==0): XCD owns contiguous tm range.
  const int bid = blockIdx.x;
  const int swz = (bid & 7) * 32 + (bid >> 3);
  const int tm = swz >> 2, tn = swz & 3;
  const size_t m0 = (size_t)tm * BM, n0 = (size_t)tn * BN;

  const int frow = lane & 15;  // fragment row/col within 16x16
  const int fcb = lane >> 4;   // k chunk 0..3
  const int swq = (frow >> 1) & 3;
  // frag read offsets (ushort idx within a plane); +mi*512 / +nj*512
  const int aoff = (wr * 128 + frow) * 32 + (fcb ^ swq) * 8;
  const int boff = (wc * 64 + frow) * 32 + (fcb ^ swq) * 8;

  // DMA staging (identical verified pattern for A and B): wave stages rows
  // [wid*32,+32) per plane as two 16-row units; lane: row += lane>>2,
  // lds chunk = lane&3, global chunk = (lane&3)^((lane>>3)&3).
  const int gch = ((lane & 3) ^ ((lane >> 3) & 3)) * 8;
  const int grow = wid * 32 + (lane >> 2);
  const unsigned short* pAx = Axb + (m0 + grow) * (size_t)K + gch;
  const unsigned short* pBx = B + (n0 + grow) * (size_t)K + gch;

  f32x4 acc[8][4];
#pragma unroll
  for (int mi = 0; mi < 8; ++mi)
#pragma unroll
    for (int nj = 0; nj < 4; ++nj)
#pragma unroll
      for (int j = 0; j < 4; ++j) acc[mi][nj][j] = 0.f;

#define ADMA(g, ks, t, NS)                                                     \
  GLOAD_LDS16(pAx + (size_t)(g)*16 * K + (size_t)(t)*64 + (ks)*32,             \
              &Asd[NS][ks][(wid * 32 + (g)*16) * 32])
#define BDMA(g, ks, t, NS)                                                     \
  GLOAD_LDS16(pBx + (size_t)(g)*16 * K + (size_t)(t)*64 + (ks)*32,             \
              &Bsd[NS][ks][(wid * 32 + (g)*16) * 32])

#define MQ(MB)                                                                 \
  LGKM0;                                                                       \
  SB0;                                                                         \
  __builtin_amdgcn_s_setprio(1);                                               \
  _Pragma("unroll") for (int i_ = 0; i_ < 4; ++i_)                             \
      _Pragma("unroll") for (int j_ = 0; j_ < 4; ++j_) acc[(MB) + i_][j_] =    \
          __builtin_amdgcn_mfma_f32_16x16x32_bf16(aq[i_], bq[j_],              \
                                                  acc[(MB) + i_][j_], 0, 0,    \
                                                  0);                          \
  __builtin_amdgcn_s_setprio(0);                                               \
  SB0;

  // TILE(S,NS,t,STG): compute tile t from slot S; stage tile t+1 into NS.
#define TILE(S, NS, t, STG)                                                    \
  {                                                                            \
    bf16x8 aq[4], bq[4];                                                       \
    /* ph0: B ks0 + A ks0 mi0-3; issue ks0 DMAs for t+1 */                     \
    _Pragma("unroll") for (int j_ = 0; j_ < 4; ++j_) bq[j_] =                  \
        *(const bf16x8*)&Bsd[S][0][boff + j_ * 512];                           \
    _Pragma("unroll") for (int i_ = 0; i_ < 4; ++i_) aq[i_] =                  \
        *(const bf16x8*)&Asd[S][0][aoff + i_ * 512];                           \
    SB0;                                                                       \
    if (STG) {                                                                 \
      ADMA(0, 0, (t) + 1, NS);                                                 \
      ADMA(1, 0, (t) + 1, NS);                                                 \
      BDMA(0, 0, (t) + 1, NS);                                                 \
      BDMA(1, 0, (t) + 1, NS);                                                 \
      SB0;                                                                     \
    }                                                                          \
    BARRIER;                                                                   \
    MQ(0);                                                                     \
    BARRIER;                                                                   \
    /* ph1: A ks0 mi4-7 (bq reused); issue ks1 DMAs for t+1 */                 \
    _Pragma("unroll") for (int i_ = 0; i_ < 4; ++i_) aq[i_] =                  \
        *(const bf16x8*)&Asd[S][0][aoff + (4 + i_) * 512];                     \
    SB0;                                                                       \
    if (STG) {                                                                 \
      ADMA(0, 1, (t) + 1, NS);                                                 \
      ADMA(1, 1, (t) + 1, NS);                                                 \
      BDMA(0, 1, (t) + 1, NS);                                                 \
      BDMA(1, 1, (t) + 1, NS);                                                 \
      SB0;                                                                     \
    }                                                                          \
    BARRIER;                                                                   \
    MQ(4);                                                                     \
    BARRIER;                                                                   \
    /* ph2: B ks1 + A ks1 mi0-3 */                                             \
    _Pragma("unroll") for (int j_ = 0; j_ < 4; ++j_) bq[j_] =                  \
        *(const bf16x8*)&Bsd[S][1][boff + j_ * 512];                           \
    _Pragma("unroll") for (int i_ = 0; i_ < 4; ++i_) aq[i_] =                  \
        *(const bf16x8*)&Asd[S][1][aoff + i_ * 512];                           \
    SB0;                                                                       \
    BARRIER;                                                                   \
    MQ(0);                                                                     \
    BARRIER;                                                                   \
    /* ph3: A ks1 mi4-7; drain t+1 DMAs (issued 2-3 phases ago), publish */    \
    _Pragma("unroll") for (int i_ = 0; i_ < 4; ++i_) aq[i_] =                  \
        *(const bf16x8*)&Asd[S][1][aoff + (4 + i_) * 512];                     \
    SB0;                                                                       \
    BARRIER;                                                                   \
    MQ(4);                                                                     \
    if (STG) {                                                                 \
      VMC(0);                                                                  \
      BARRIER;                                                                 \
    }                                                                          \
  }

  // ---- prologue: stage tile 0 -> slot 0 ----
  ADMA(0, 0, 0, 0);
  ADMA(1, 0, 0, 0);
  BDMA(0, 0, 0, 0);
  BDMA(1, 0, 0, 0);
  ADMA(0, 1, 0, 0);
  ADMA(1, 1, 0, 0);
  BDMA(0, 1, 0, 0);
  BDMA(1, 1, 0, 0);
  SB0;
  VMC(0);
  BARRIER;

  // ---- main loop: 32 K-tiles ----
  for (int t = 0; t < NKT - 2; t += 2) {
    TILE(0, 1, t, 1);
    TILE(1, 0, t + 1, 1);
  }
  TILE(0, 1, NKT - 2, 1);  // t=30: stages tile 31 -> slot1
  TILE(1, 0, NKT - 1, 0);  // t=31: no stage

#undef ADMA
#undef BDMA
#undef MQ
#undef TILE

  // ---- epilogue 1: fused column partial stats from live accumulators ----
  // C/D layout: col = wc*64 + nj*16 + frow, row = wr*128 + mi*16 + fcb*4 + j
#pragma unroll
  for (int nj = 0; nj < 4; ++nj) {
    float s = 0.f, q = 0.f;
#pragma unroll
    for (int mi = 0; mi < 8; ++mi)
#pragma unroll
      for (int j = 0; j < 4; ++j) {
        float v = acc[mi][nj][j];
        s += v;
        q += v * v;
      }
    s += __shfl_xor(s, 16);  // reduce over fcb (lane bits 4-5)
    s += __shfl_xor(s, 32);
    q += __shfl_xor(q, 16);
    q += __shfl_xor(q, 32);
    if (fcb == 0) {
      redsum[wr][wc * 64 + nj * 16 + frow] = s;
      redsq[wr][wc * 64 + nj * 16 + frow] = q;
    }
  }
  __syncthreads();
  if (tid < BN) {
    psum[(size_t)tm * N + n0 + tid] = redsum[0][tid] + redsum[1][tid];
    psq[(size_t)tm * N + n0 + tid] = redsq[0][tid] + redsq[1][tid];
  }

  // ---- epilogue 2: store Y fp32 (raw pre-BN accumulators) ----
#pragma unroll
  for (int mi = 0; mi < 8; ++mi) {
    const size_t r0 = m0 + wr * 128 + mi * 16 + fcb * 4;
#pragma unroll
    for (int nj = 0; nj < 4; ++nj) {
      float* yp = Y + r0 * N + n0 + wc * 64 + nj * 16 + frow;
#pragma unroll
      for (int j = 0; j < 4; ++j) yp[(size_t)j * N] = acc[mi][nj][j];
    }
  }
}

// ---- PATH B (fallback if workspace too small): R7 kernel, A fp32 reg-cast ----
__global__ __launch_bounds__(512, 2) void gemm_fb_kernel(
    const float* __restrict__ Af, const unsigned short* __restrict__ B,
    float* __restrict__ Y, float* __restrict__ psum, float* __restrict__ psq) {
  __shared__ unsigned short Asd[2][2][8192];
  __shared__ unsigned short Bsd[2][2][8192];
  __shared__ float redsum[2][256];
  __shared__ float redsq[2][256];

  const int tid = threadIdx.x;
  const int wid = tid >> 6;
  const int lane = tid & 63;
  const int wr = wid >> 2, wc = wid & 3;

  const int bid = blockIdx.x;
  const int swz = (bid & 7) * 32 + (bid >> 3);
  const int tm = swz >> 2, tn = swz & 3;
  const size_t m0 = (size_t)tm * BM, n0 = (size_t)tn * BN;

  const int frow = lane & 15;
  const int fcb = lane >> 4;
  const int swq = (frow >> 1) & 3;
  const int aoff = (wr * 128 + frow) * 32 + (fcb ^ swq) * 8;
  const int boff = (wc * 64 + frow) * 32 + (fcb ^ swq) * 8;

  const unsigned short* pBg = B + (n0 + wid * 32 + (lane >> 2)) * (size_t)K +
                              (((lane & 3) ^ ((lane >> 3) & 3)) * 8);
  const size_t aRowK = (m0 + wid * 32 + (lane >> 2)) * (size_t)K;
  const float* pAg = Af + aRowK + (((lane & 3) ^ ((lane >> 3) & 3)) * 8);
  const int awb = (wid * 32 + (lane >> 2)) * 32 + (lane & 3) * 8;

  f32x4 acc[8][4];
#pragma unroll
  for (int mi = 0; mi < 8; ++mi)
#pragma unroll
    for (int nj = 0; nj < 4; ++nj)
#pragma unroll
      for (int j = 0; j < 4; ++j) acc[mi][nj][j] = 0.f;

  f32x4 xq0, xq1, xq2, xq3, xq4, xq5, xq6, xq7;

#define BG(g, ks, t, NS)                                                       \
  GLOAD_LDS16(pBg + (size_t)(g)*16 * K + (size_t)(t)*64 + (ks)*32,             \
              &Bsd[NS][ks][(wid * 32 + (g)*16) * 32])
#define ALOAD(t)                                                               \
  {                                                                            \
    const float* p_ = pAg + (size_t)(t)*64;                                    \
    xq0 = *(const f32x4*)(p_);                                                 \
    xq1 = *(const f32x4*)(p_ + 4);                                             \
    xq2 = *(const f32x4*)(p_ + 16 * (size_t)K);                                \
    xq3 = *(const f32x4*)(p_ + 16 * (size_t)K + 4);                            \
    xq4 = *(const f32x4*)(p_ + 32);                                            \
    xq5 = *(const f32x4*)(p_ + 36);                                            \
    xq6 = *(const f32x4*)(p_ + 16 * (size_t)K + 32);                           \
    xq7 = *(const f32x4*)(p_ + 16 * (size_t)K + 36);                           \
  }
#define CVW(dst, ra, rb)                                                       \
  {                                                                            \
    bf16x8 v_;                                                                 \
    _Pragma("unroll") for (int j_ = 0; j_ < 4; ++j_) {                         \
      v_[j_] = (__bf16)(ra)[j_];                                               \
      v_[4 + j_] = (__bf16)(rb)[j_];                                           \
    }                                                                          \
    *(bf16x8*)(dst) = v_;                                                      \
  }
#define AWRITE(NS)                                                             \
  {                                                                            \
    CVW(&Asd[NS][0][awb], xq0, xq1);                                           \
    CVW(&Asd[NS][0][awb + 512], xq2, xq3);                                     \
    CVW(&Asd[NS][1][awb], xq4, xq5);                                           \
    CVW(&Asd[NS][1][awb + 512], xq6, xq7);                                     \
  }
#define MQ(MB)                                                                 \
  LGKM0;                                                                       \
  SB0;                                                                         \
  __builtin_amdgcn_s_setprio(1);                                               \
  _Pragma("unroll") for (int i_ = 0; i_ < 4; ++i_)                             \
      _Pragma("unroll") for (int j_ = 0; j_ < 4; ++j_) acc[(MB) + i_][j_] =    \
          __builtin_amdgcn_mfma_f32_16x16x32_bf16(aq[i_], bq[j_],              \
                                                  acc[(MB) + i_][j_], 0, 0,    \
                                                  0);                          \
  __builtin_amdgcn_s_setprio(0);                                               \
  SB0;

#define TILE(S, NS, t, STG)                                                    \
  {                                                                            \
    bf16x8 aq[4], bq[4];                                                       \
    _Pragma("unroll") for (int j_ = 0; j_ < 4; ++j_) bq[j_] =                  \
        *(const bf16x8*)&Bsd[S][0][boff + j_ * 512];                           \
    _Pragma("unroll") for (int i_ = 0; i_ < 4; ++i_) aq[i_] =                  \
        *(const bf16x8*)&Asd[S][0][aoff + i_ * 512];                           \
    SB0;                                                                       \
    if (STG) {                                                                 \
      BG(0, 0, (t) + 1, NS);                                                   \
      BG(1, 0, (t) + 1, NS);                                                   \
      SB0;                                                                     \
    }                                                                          \
    BARRIER;                                                                   \
    MQ(0);                                                                     \
    BARRIER;                                                                   \
    _Pragma("unroll") for (int i_ = 0; i_ < 4; ++i_) aq[i_] =                  \
        *(const bf16x8*)&Asd[S][0][aoff + (4 + i_) * 512];                     \
    SB0;                                                                       \
    if (STG) {                                                                 \
      BG(0, 1, (t) + 1, NS);                                                   \
      BG(1, 1, (t) + 1, NS);                                                   \
      SB0;                                                                     \
      ALOAD((t) + 1);                                                          \
      SB0;                                                                     \
    }                                                                          \
    BARRIER;                                                                   \
    MQ(4);                                                                     \
    BARRIER;                                                                   \
    _Pragma("unroll") for (int j_ = 0; j_ < 4; ++j_) bq[j_] =                  \
        *(const bf16x8*)&Bsd[S][1][boff + j_ * 512];                           \
    _Pragma("unroll") for (int i_ = 0; i_ < 4; ++i_) aq[i_] =                  \
        *(const bf16x8*)&Asd[S][1][aoff + i_ * 512];                           \
    SB0;                                                                       \
    BARRIER;                                                                   \
    MQ(0);                                                                     \
    BARRIER;                                                                   \
    _Pragma("unroll") for (int i_ = 0; i_ < 4; ++i_) aq[i_] =                  \
        *(const bf16x8*)&Asd[S][1][aoff + (4 + i_) * 512];                     \
    SB0;                                                                       \
    if (STG) {                                                                 \
      AWRITE(NS);                                                              \
      SB0;                                                                     \
    }                                                                          \
    BARRIER;                                                                   \
    MQ(4);                                                                     \
    if (STG) BARRIER;                                                          \
  }

  BG(0, 0, 0, 0);
  BG(1, 0, 0, 0);
  BG(0, 1, 0, 0);
  BG(1, 1, 0, 0);
  SB0;
  ALOAD(0);
  SB0;
  AWRITE(0);
  LGKM0;
  BARRIER;

  for (int t = 0; t < NKT - 2; t += 2) {
    TILE(0, 1, t, 1);
    TILE(1, 0, t + 1, 1);
  }
  TILE(0, 1, NKT - 2, 1);
  TILE(1, 0, NKT - 1, 0);

#undef BG
#undef ALOAD
#undef CVW
#undef AWRITE
#undef MQ
#undef TILE

#pragma unroll
  for (int nj = 0; nj < 4; ++nj) {
    float s = 0.f, q = 0.f;
#pragma unroll
    for (int mi = 0; mi < 8; ++mi)
#pragma unroll
      for (int j = 0; j < 4; ++j) {
        float v = acc[mi][nj][j];
        s += v;
        q += v * v;
      }
    s += __shfl_xor(s, 16);
    s += __shfl_xor(s, 32);
    q += __shfl_xor(q, 16);
    q += __shfl_xor(q, 32);
    if (fcb == 0) {
      redsum[wr][wc * 64 + nj * 16 + frow] = s;
      redsq[wr][wc * 64 + nj * 16 + frow] = q;
    }
  }
  __syncthreads();
  if (tid < BN) {
    psum[(size_t)tm * N + n0 + tid] = redsum[0][tid] + redsum[1][tid];
    psq[(size_t)tm * N + n0 + tid] = redsq[0][tid] + redsq[1][tid];
  }
#pragma unroll
  for (int mi = 0; mi < 8; ++mi) {
    const size_t r0 = m0 + wr * 128 + mi * 16 + fcb * 4;
#pragma unroll
    for (int nj = 0; nj < 4; ++nj) {
      float* yp = Y + r0 * N + n0 + wc * 64 + nj * 16 + frow;
#pragma unroll
      for (int j = 0; j < 4; ++j) yp[(size_t)j * N] = acc[mi][nj][j];
    }
  }
}

// ---- finalize BN stats -> per-column scale/shift ----
__global__ __launch_bounds__(256) void bnstats_kernel(
    const float* __restrict__ psum, const float* __restrict__ psq,
    const float* __restrict__ gamma, const float* __restrict__ beta,
    float* __restrict__ scale, float* __restrict__ shift) {
  const int c = blockIdx.x * 256 + threadIdx.x;
  float s = 0.f, q = 0.f;
  for (int i = 0; i < TM2; ++i) {
    s += psum[i * N + c];
    q += psq[i * N + c];
  }
  const float mean = s * (1.f / (float)M);
  const float var = q * (1.f / (float)M) - mean * mean;
  const float inv = rsqrtf(var + BN_EPS);
  const float sc = gamma[c] * inv;
  scale[c] = sc;
  shift[c] = beta[c] - mean * sc;
}

// ---- apply BN in place on fp32 Y (= d_out), 4 floats / thread ----
__global__ __launch_bounds__(256) void bnapply_kernel(
    float* __restrict__ Y, const float* __restrict__ scale,
    const float* __restrict__ shift) {
  const size_t i = (size_t)blockIdx.x * 256 + threadIdx.x;
  f32x4 y = ((const f32x4*)Y)[i];
  const int c = (int)((i * 4) & (N - 1));
  f32x4 sc = *(const f32x4*)&scale[c];
  f32x4 sh = *(const f32x4*)&shift[c];
  ((f32x4*)Y)[i] = y * sc + sh;
}

extern "C" void kernel_launch(void* const* d_in, const int* in_sizes, int n_in,
                              void* d_out, int out_size, void* d_ws,
                              size_t ws_size, hipStream_t stream) {
  const float* x = (const float*)d_in[0];
  const float* w = (const float*)d_in[1];
  // d_in[2] = bias: a per-column constant shift cancels exactly in BatchNorm
  const float* gamma = (const float*)d_in[3];
  const float* beta = (const float*)d_in[4];
  float* Y = (float*)d_out;  // y staged here fp32, normalized in place

  char* ws = (char*)d_ws;
  uint4v* wb = (uint4v*)ws;  // 4 MiB
  float* psum = (float*)(ws + ((size_t)4 << 20));
  float* psq = psum + (size_t)TM2 * N;  // 256 KiB each
  float* scale = psq + (size_t)TM2 * N;
  float* shift = scale + N;
  unsigned short* xb = (unsigned short*)(ws + ((size_t)8 << 20));  // 64 MiB
  const size_t need = ((size_t)8 << 20) + (size_t)M * K * 2;

  binw_kernel<<<(N * K / 8) / 256, 256, 0, stream>>>(w, wb);

  if (ws_size >= need) {
    castx_kernel<<<(int)(((size_t)M * K / 8) / 256), 256, 0, stream>>>(x, xb);
    gemm_dma_kernel<<<(M / BM) * (N / BN), 512, 0, stream>>>(
        xb, (const unsigned short*)wb, Y, psum, psq);
  } else {
    gemm_fb_kernel<<<(M / BM) * (N / BN), 512, 0, stream>>>(
        x, (const unsigned short*)wb, Y, psum, psq);
  }
  bnstats_kernel<<<N / 256, 256, 0, stream>>>(psum, psq, gamma, beta, scale,
                                              shift);
  bnapply_kernel<<<(M * N / 4) / 256, 256, 0, stream>>>(Y, scale, shift);
}